// Round 2
// baseline (1860.180 us; speedup 1.0000x reference)
//
#include <hip/hip_runtime.h>

// Problem constants (shapes fixed by the reference)
#define HP    1017
#define WP    1017
#define NPIX  (HP*WP)          // 1034289
#define N3    (NPIX/3)         // 344763
#define W_IMG 1024
#define RATE  0.001f
#define EPSV  1e-7f
#define CHUNK 1024

// ---------------------------------------------------------------------------
// init: t0 = tlb = max_c(1 - center/A), and pack img_c = img[:HP,:WP,:] contiguously
// ---------------------------------------------------------------------------
__global__ void init_kernel(const float* __restrict__ img, const float* __restrict__ A,
                            float* __restrict__ img_c, float* __restrict__ t0) {
    int b = blockIdx.x * blockDim.x + threadIdx.x;
    int a = blockIdx.y;
    if (b >= WP) return;
    int m = a * WP + b;
    float A0 = A[0], A1 = A[1], A2 = A[2];
    const float* src = img + ((size_t)a * W_IMG + b) * 3;
    img_c[3*m+0] = src[0]; img_c[3*m+1] = src[1]; img_c[3*m+2] = src[2];
    const float* cen = img + ((size_t)(a+3) * W_IMG + (b+3)) * 3;
    float t = 1.0f - cen[0] / A0;
    t = fmaxf(t, 1.0f - cen[1] / A1);
    t = fmaxf(t, 1.0f - cen[2] / A2);
    t0[m] = t;
}

// ---------------------------------------------------------------------------
// standalone sig (used once, for sig0/lg0 from the initial t)
// ---------------------------------------------------------------------------
__global__ void sig_kernel(const float* __restrict__ t, const float* __restrict__ img_c,
                           const float* __restrict__ A,
                           float* __restrict__ sig, float* __restrict__ lgarr) {
    int m = blockIdx.x * blockDim.x + threadIdx.x;
    if (m >= NPIX) return;
    float A0 = A[0], A1 = A[1], A2 = A[2];
    float t0 = t[m];
    float tm = t[m > 0 ? m - 1 : 0];
    float tp = t[m < NPIX-1 ? m + 1 : NPIX-1];
    float r0 = 1.0f / t0, rm = 1.0f / tm, rp = 1.0f / tp;
    int base = 3 * m;
    float fm1 = img_c[m > 0        ? base - 1 : 0];
    float f0  = img_c[base + 0];
    float f1  = img_c[base + 1];
    float f2  = img_c[base + 2];
    float f3  = img_c[m < NPIX - 1 ? base + 3 : base + 2];
    float dm1 = (fm1 - A2) * rm + A2;
    float d0  = (f0  - A0) * r0 + A0;
    float d1  = (f1  - A1) * r0 + A1;
    float d2  = (f2  - A2) * r0 + A2;
    float d3  = (f3  - A0) * rp + A0;
    float y0 = 0.5f * (d1 - dm1);
    float y1 = 0.5f * (d2 - d0);
    float y2 = 0.5f * (d3 - d1);
    if (m == 0      ) y0 = d1 - d0;
    if (m == N3     ) y0 = d1 - d0;
    if (m == 2*N3   ) y0 = d1 - d0;
    if (m == N3 - 1 ) y2 = d2 - d1;
    if (m == 2*N3-1 ) y2 = d2 - d1;
    if (m == NPIX-1 ) y2 = d2 - d1;
    float l2 = sqrtf(y0*y0 + y1*y1 + y2*y2);
    sig[m] = 1.0f / (1.0f + expf(48.0f * (l2 - 0.1f)));
    lgarr[m] = logf(t0 <= 0.0f ? EPSV : t0);
}

// ---------------------------------------------------------------------------
// one GD-update stencil at flat index m (reads old t/lg/sig)
// ---------------------------------------------------------------------------
__device__ __forceinline__ float tnew_at(int m, const float* __restrict__ t,
                                         const float* __restrict__ lg,
                                         const float* __restrict__ sig) {
    int a = m / WP;
    int b = m - a * WP;
    float tc = t[m];
    float w0 = (tc <= 0.0f) ? EPSV : tc;
    float lgC = lg[m];
    float acc = 0.0f;
    if (b >= 1) {
        float lgW = (b >= 2) ? lg[m-2] : 0.0f;
        acc += (lgC - lgW) * sig[m-1];
    }
    if (b <= WP-2) {
        float lgE = (b <= WP-3) ? lg[m+2] : 0.0f;
        acc -= (lgE - lgC) * sig[m+1];
    }
    if (a <= HP-2) {
        float lgS = (a <= HP-3) ? lg[m+2*WP] : 0.0f;
        acc += (lgC - lgS) * sig[m+WP];
    }
    if (a >= 1) {
        float lgN = (a >= 2) ? lg[m-2*WP] : 0.0f;
        acc -= (lgN - lgC) * sig[m-WP];
    }
    return w0 - RATE * (2.0f * acc / w0);
}

// ---------------------------------------------------------------------------
// fused: t_new = GD step, then sig/lg from t_new (t_new shared via regs + LDS edges)
// ---------------------------------------------------------------------------
__global__ __launch_bounds__(256) void fused_kernel(
    const float* __restrict__ t, const float* __restrict__ lg, const float* __restrict__ sig,
    const float* __restrict__ img_c, const float* __restrict__ A,
    float* __restrict__ tout, float* __restrict__ sigout, float* __restrict__ lgout)
{
    __shared__ float tl[CHUNK + 2];     // tl[k] = t_new[s - 1 + k]
    const int s   = blockIdx.x * CHUNK;
    const int tid = threadIdx.x;
    const int m0  = s + 4 * tid;

    float tn[4];
    bool  act[4];
    #pragma unroll
    for (int j = 0; j < 4; ++j) {
        int m = m0 + j;
        act[j] = (m < NPIX);
        if (act[j]) tn[j] = tnew_at(m, t, lg, sig);
    }
    // publish chunk-internal boundary values
    if (act[0]) tl[4*tid + 1] = tn[0];
    if (act[3]) tl[4*tid + 4] = tn[3];
    // halo: thread 0 recomputes the two out-of-chunk stencils
    if (tid == 0) {
        tl[0] = tnew_at(s > 0 ? s - 1 : 0, t, lg, sig);
        int mr = s + CHUNK; if (mr > NPIX - 1) mr = NPIX - 1;
        tl[CHUNK + 1] = tnew_at(mr, t, lg, sig);
    }
    // store t_new (vectorized)
    if (act[3]) {
        *(float4*)(tout + m0) = make_float4(tn[0], tn[1], tn[2], tn[3]);
    } else {
        #pragma unroll
        for (int j = 0; j < 4; ++j) if (act[j]) tout[m0 + j] = tn[j];
    }
    __syncthreads();

    const float A0 = A[0], A1 = A[1], A2 = A[2];
    float tL = tl[4*tid];        // t_new[m0-1]
    float tR = tl[4*tid + 5];    // t_new[m0+4]
    float rn[4], sg[4], lgv[4];
    float rL = 1.0f / tL, rR = 1.0f / tR;
    #pragma unroll
    for (int j = 0; j < 4; ++j) if (act[j]) rn[j] = 1.0f / tn[j];

    #pragma unroll
    for (int j = 0; j < 4; ++j) {
        if (!act[j]) continue;
        int m = m0 + j;
        float t0 = tn[j];
        float r0 = rn[j];
        float rm = (j > 0) ? rn[j-1] : rL;
        float rp = (j < 3) ? rn[j+1] : rR;
        if (m == 0)        rm = r0;
        if (m == NPIX - 1) rp = r0;
        int base = 3 * m;
        float fm1 = img_c[m > 0        ? base - 1 : 0];
        float f0  = img_c[base + 0];
        float f1  = img_c[base + 1];
        float f2  = img_c[base + 2];
        float f3  = img_c[m < NPIX - 1 ? base + 3 : base + 2];
        float dm1 = (fm1 - A2) * rm + A2;
        float d0  = (f0  - A0) * r0 + A0;
        float d1  = (f1  - A1) * r0 + A1;
        float d2  = (f2  - A2) * r0 + A2;
        float d3  = (f3  - A0) * rp + A0;
        float y0 = 0.5f * (d1 - dm1);
        float y1 = 0.5f * (d2 - d0);
        float y2 = 0.5f * (d3 - d1);
        if (m == 0      ) y0 = d1 - d0;
        if (m == N3     ) y0 = d1 - d0;
        if (m == 2*N3   ) y0 = d1 - d0;
        if (m == N3 - 1 ) y2 = d2 - d1;
        if (m == 2*N3-1 ) y2 = d2 - d1;
        if (m == NPIX-1 ) y2 = d2 - d1;
        float l2 = sqrtf(y0*y0 + y1*y1 + y2*y2);
        sg[j]  = 1.0f / (1.0f + expf(48.0f * (l2 - 0.1f)));
        lgv[j] = logf(t0 <= 0.0f ? EPSV : t0);
    }
    if (act[3]) {
        *(float4*)(sigout + m0) = make_float4(sg[0], sg[1], sg[2], sg[3]);
        *(float4*)(lgout  + m0) = make_float4(lgv[0], lgv[1], lgv[2], lgv[3]);
    } else {
        #pragma unroll
        for (int j = 0; j < 4; ++j) if (act[j]) { sigout[m0+j] = sg[j]; lgout[m0+j] = lgv[j]; }
    }
}

// ---------------------------------------------------------------------------
// final dehaze into d_out
// ---------------------------------------------------------------------------
__global__ void out_kernel(const float* __restrict__ t, const float* __restrict__ img_c,
                           const float* __restrict__ A, float* __restrict__ out) {
    int m = blockIdx.x * blockDim.x + threadIdx.x;
    if (m >= NPIX) return;
    float tv = t[m];
    float A0 = A[0], A1 = A[1], A2 = A[2];
    out[3*m+0] = (img_c[3*m+0] - A0) / tv + A0;
    out[3*m+1] = (img_c[3*m+1] - A1) / tv + A1;
    out[3*m+2] = (img_c[3*m+2] - A2) / tv + A2;
}

extern "C" void kernel_launch(void* const* d_in, const int* in_sizes, int n_in,
                              void* d_out, int out_size, void* d_ws, size_t ws_size,
                              hipStream_t stream) {
    const float* img = (const float*)d_in[0];
    const float* A   = (const float*)d_in[1];
    // workspace (floats): img_c[3N] | t_a[N] | t_b[N] | sig_a[N] | sig_b[N] | lg_a[N] | lg_b[N]
    float* ws    = (float*)d_ws;
    float* img_c = ws;
    float* t_a   = ws + (size_t)3 * NPIX;
    float* t_b   = t_a + NPIX;
    float* sig_a = t_b + NPIX;
    float* sig_b = sig_a + NPIX;
    float* lg_a  = sig_b + NPIX;
    float* lg_b  = lg_a + NPIX;

    dim3 blk2(256, 1, 1);
    dim3 grd2((WP + 255) / 256, HP, 1);
    int blk1 = 256;
    int grd1 = (NPIX + blk1 - 1) / blk1;
    int grdF = (NPIX + CHUNK - 1) / CHUNK;

    hipLaunchKernelGGL(init_kernel, grd2, blk2, 0, stream, img, A, img_c, t_a);
    hipLaunchKernelGGL(sig_kernel, dim3(grd1), dim3(blk1), 0, stream, t_a, img_c, A, sig_a, lg_a);

    float* tsrc = t_a;  float* tdst = t_b;
    float* ssrc = sig_a; float* sdst = sig_b;
    float* gsrc = lg_a;  float* gdst = lg_b;
    for (int it = 0; it < 100; ++it) {
        hipLaunchKernelGGL(fused_kernel, dim3(grdF), dim3(256), 0, stream,
                           tsrc, gsrc, ssrc, img_c, A, tdst, sdst, gdst);
        float* tmp;
        tmp = tsrc; tsrc = tdst; tdst = tmp;
        tmp = ssrc; ssrc = sdst; sdst = tmp;
        tmp = gsrc; gsrc = gdst; gdst = tmp;
    }
    hipLaunchKernelGGL(out_kernel, dim3(grd1), dim3(blk1), 0, stream, tsrc, img_c, A, (float*)d_out);
}

// Round 3
// 1093.349 us; speedup vs baseline: 1.7014x; 1.7014x over previous
//
#include <hip/hip_runtime.h>

// Problem constants (shapes fixed by the reference)
#define HP    1017
#define WP    1017
#define NPIX  (HP*WP)          // 1034289
#define N3    (NPIX/3)         // 344763
#define W_IMG 1024
#define RATE  0.001f
#define EPSV  1e-7f

// ---------------------------------------------------------------------------
// init: t0 = tlb = max_c(1 - center/A), and pack img_c = img[:HP,:WP,:] contiguously
// ---------------------------------------------------------------------------
__global__ void init_kernel(const float* __restrict__ img, const float* __restrict__ A,
                            float* __restrict__ img_c, float* __restrict__ t0) {
    int b = blockIdx.x * blockDim.x + threadIdx.x;
    int a = blockIdx.y;
    if (b >= WP) return;
    int m = a * WP + b;
    float A0 = A[0], A1 = A[1], A2 = A[2];
    const float* src = img + ((size_t)a * W_IMG + b) * 3;
    img_c[3*m+0] = src[0]; img_c[3*m+1] = src[1]; img_c[3*m+2] = src[2];
    const float* cen = img + ((size_t)(a+3) * W_IMG + (b+3)) * 3;
    float t = 1.0f - cen[0] / A0;
    t = fmaxf(t, 1.0f - cen[1] / A1);
    t = fmaxf(t, 1.0f - cen[2] / A2);
    t0[m] = t;
}

// ---------------------------------------------------------------------------
// standalone sig (used once, for sig0/lg0 from the initial t)
// ---------------------------------------------------------------------------
__global__ void sig_kernel(const float* __restrict__ t, const float* __restrict__ img_c,
                           const float* __restrict__ A,
                           float* __restrict__ sig, float* __restrict__ lgarr) {
    int m = blockIdx.x * blockDim.x + threadIdx.x;
    if (m >= NPIX) return;
    float A0 = A[0], A1 = A[1], A2 = A[2];
    float t0 = t[m];
    float tm = t[m > 0 ? m - 1 : 0];
    float tp = t[m < NPIX-1 ? m + 1 : NPIX-1];
    float r0 = 1.0f / t0, rm = 1.0f / tm, rp = 1.0f / tp;
    int base = 3 * m;
    float fm1 = img_c[m > 0        ? base - 1 : 0];
    float f0  = img_c[base + 0];
    float f1  = img_c[base + 1];
    float f2  = img_c[base + 2];
    float f3  = img_c[m < NPIX - 1 ? base + 3 : base + 2];
    float dm1 = (fm1 - A2) * rm + A2;
    float d0  = (f0  - A0) * r0 + A0;
    float d1  = (f1  - A1) * r0 + A1;
    float d2  = (f2  - A2) * r0 + A2;
    float d3  = (f3  - A0) * rp + A0;
    float y0 = 0.5f * (d1 - dm1);
    float y1 = 0.5f * (d2 - d0);
    float y2 = 0.5f * (d3 - d1);
    if (m == 0      ) y0 = d1 - d0;
    if (m == N3     ) y0 = d1 - d0;
    if (m == 2*N3   ) y0 = d1 - d0;
    if (m == N3 - 1 ) y2 = d2 - d1;
    if (m == 2*N3-1 ) y2 = d2 - d1;
    if (m == NPIX-1 ) y2 = d2 - d1;
    float l2 = sqrtf(y0*y0 + y1*y1 + y2*y2);
    sig[m] = 1.0f / (1.0f + expf(48.0f * (l2 - 0.1f)));
    lgarr[m] = logf(t0 <= 0.0f ? EPSV : t0);
}

// ---------------------------------------------------------------------------
// one GD-update stencil at flat index m (reads old t/lg/sig)
// ---------------------------------------------------------------------------
__device__ __forceinline__ float tnew_at(int m, const float* __restrict__ t,
                                         const float* __restrict__ lg,
                                         const float* __restrict__ sig) {
    int a = m / WP;
    int b = m - a * WP;
    float tc = t[m];
    float w0 = (tc <= 0.0f) ? EPSV : tc;
    float lgC = lg[m];
    float acc = 0.0f;
    if (b >= 1) {
        float lgW = (b >= 2) ? lg[m-2] : 0.0f;
        acc += (lgC - lgW) * sig[m-1];
    }
    if (b <= WP-2) {
        float lgE = (b <= WP-3) ? lg[m+2] : 0.0f;
        acc -= (lgE - lgC) * sig[m+1];
    }
    if (a <= HP-2) {
        float lgS = (a <= HP-3) ? lg[m+2*WP] : 0.0f;
        acc += (lgC - lgS) * sig[m+WP];
    }
    if (a >= 1) {
        float lgN = (a >= 2) ? lg[m-2*WP] : 0.0f;
        acc -= (lgN - lgC) * sig[m-WP];
    }
    return w0 - RATE * (2.0f * acc / w0);
}

// ---------------------------------------------------------------------------
// fused iteration: t_new (1:1 coalesced), reciprocals via LDS, then sig/lg of t_new
// ---------------------------------------------------------------------------
__global__ __launch_bounds__(256) void fused_kernel(
    const float* __restrict__ t, const float* __restrict__ lg, const float* __restrict__ sig,
    const float* __restrict__ img_c, const float* __restrict__ A,
    float* __restrict__ tout, float* __restrict__ sigout, float* __restrict__ lgout)
{
    __shared__ float rl[258];          // rl[k] = 1 / t_new[s - 1 + k]
    const int s   = blockIdx.x * 256;
    const int tid = threadIdx.x;
    const int m   = s + tid;
    const bool active = (m < NPIX);

    float tn = 1.0f, r0 = 1.0f;
    if (active) {
        tn = tnew_at(m, t, lg, sig);
        r0 = 1.0f / tn;
        rl[tid + 1] = r0;
        tout[m] = tn;
    }
    if (tid == 0) {                    // left halo (wave 0)
        rl[0] = 1.0f / tnew_at(s > 0 ? s - 1 : 0, t, lg, sig);
    } else if (tid == 64) {            // right halo (wave 1, runs in parallel)
        int mr = s + 256; if (mr > NPIX - 1) mr = NPIX - 1;
        rl[257] = 1.0f / tnew_at(mr, t, lg, sig);
    }
    __syncthreads();
    if (!active) return;

    const float A0 = A[0], A1 = A[1], A2 = A[2];
    float rm = (m > 0)        ? rl[tid]     : r0;
    float rp = (m < NPIX - 1) ? rl[tid + 2] : r0;
    int base = 3 * m;
    float fm1 = img_c[m > 0        ? base - 1 : 0];
    float f0  = img_c[base + 0];
    float f1  = img_c[base + 1];
    float f2  = img_c[base + 2];
    float f3  = img_c[m < NPIX - 1 ? base + 3 : base + 2];
    float dm1 = (fm1 - A2) * rm + A2;
    float d0  = (f0  - A0) * r0 + A0;
    float d1  = (f1  - A1) * r0 + A1;
    float d2  = (f2  - A2) * r0 + A2;
    float d3  = (f3  - A0) * rp + A0;
    float y0 = 0.5f * (d1 - dm1);
    float y1 = 0.5f * (d2 - d0);
    float y2 = 0.5f * (d3 - d1);
    if (m == 0      ) y0 = d1 - d0;
    if (m == N3     ) y0 = d1 - d0;
    if (m == 2*N3   ) y0 = d1 - d0;
    if (m == N3 - 1 ) y2 = d2 - d1;
    if (m == 2*N3-1 ) y2 = d2 - d1;
    if (m == NPIX-1 ) y2 = d2 - d1;
    float l2 = sqrtf(y0*y0 + y1*y1 + y2*y2);
    sigout[m] = 1.0f / (1.0f + expf(48.0f * (l2 - 0.1f)));
    lgout[m]  = logf(tn <= 0.0f ? EPSV : tn);
}

// ---------------------------------------------------------------------------
// final iteration fused with dehaze output (no neighbor exchange needed)
// ---------------------------------------------------------------------------
__global__ __launch_bounds__(256) void fused_final_kernel(
    const float* __restrict__ t, const float* __restrict__ lg, const float* __restrict__ sig,
    const float* __restrict__ img_c, const float* __restrict__ A,
    float* __restrict__ out)
{
    int m = blockIdx.x * blockDim.x + threadIdx.x;
    if (m >= NPIX) return;
    float tn = tnew_at(m, t, lg, sig);
    float A0 = A[0], A1 = A[1], A2 = A[2];
    float r = 1.0f / tn;
    out[3*m+0] = (img_c[3*m+0] - A0) * r + A0;
    out[3*m+1] = (img_c[3*m+1] - A1) * r + A1;
    out[3*m+2] = (img_c[3*m+2] - A2) * r + A2;
}

extern "C" void kernel_launch(void* const* d_in, const int* in_sizes, int n_in,
                              void* d_out, int out_size, void* d_ws, size_t ws_size,
                              hipStream_t stream) {
    const float* img = (const float*)d_in[0];
    const float* A   = (const float*)d_in[1];
    // workspace (floats): img_c[3N] | t_a[N] | t_b[N] | sig_a[N] | sig_b[N] | lg_a[N] | lg_b[N]
    float* ws    = (float*)d_ws;
    float* img_c = ws;
    float* t_a   = ws + (size_t)3 * NPIX;
    float* t_b   = t_a + NPIX;
    float* sig_a = t_b + NPIX;
    float* sig_b = sig_a + NPIX;
    float* lg_a  = sig_b + NPIX;
    float* lg_b  = lg_a + NPIX;

    dim3 blk2(256, 1, 1);
    dim3 grd2((WP + 255) / 256, HP, 1);
    int blk1 = 256;
    int grd1 = (NPIX + blk1 - 1) / blk1;   // 4041

    hipLaunchKernelGGL(init_kernel, grd2, blk2, 0, stream, img, A, img_c, t_a);
    hipLaunchKernelGGL(sig_kernel, dim3(grd1), dim3(blk1), 0, stream, t_a, img_c, A, sig_a, lg_a);

    float* tsrc = t_a;   float* tdst = t_b;
    float* ssrc = sig_a; float* sdst = sig_b;
    float* gsrc = lg_a;  float* gdst = lg_b;
    for (int it = 0; it < 99; ++it) {
        hipLaunchKernelGGL(fused_kernel, dim3(grd1), dim3(blk1), 0, stream,
                           tsrc, gsrc, ssrc, img_c, A, tdst, sdst, gdst);
        float* tmp;
        tmp = tsrc; tsrc = tdst; tdst = tmp;
        tmp = ssrc; ssrc = sdst; sdst = tmp;
        tmp = gsrc; gsrc = gdst; gdst = tmp;
    }
    // iteration 100 fused with the final dehaze
    hipLaunchKernelGGL(fused_final_kernel, dim3(grd1), dim3(blk1), 0, stream,
                       tsrc, gsrc, ssrc, img_c, A, (float*)d_out);
}